// Round 2
// baseline (312.879 us; speedup 1.0000x reference)
//
#include <hip/hip_runtime.h>

// MRR on MI355X — R8: fused cooperative kernel, hardened + fallback.
// N_TOT = 8192 + 8192*4000 = 32,776,192 elems; nvec = N_TOT/4 vint4.
//
// Evidence trail:
//  - ~225 us of dur_us is harness poison fills (3x 512MB @ ~7 TB/s),
//    irreducible. Kernel budget ~60 us (two-kernel R6). Data floor:
//    idx 131MB + pv 131MB = 262MB ~= 38-40 us @ achievable HBM BW.
//  - R7 (fused, GRID=512 coop) FAILED with outputs never written
//    (absmax 1.0 / poison 468 in out) and NO hang => the cooperative
//    launch itself was rejected (return code was unchecked; 512 blocks
//    was exactly at the 2-blk/CU occupancy boundary).
//  - R5 lesson: NO __threadfence (emits buffer_wbl2+buffer_inv, 3x slower).
//    Proven-safe cross-block mechanism: atomic RMWs execute at the
//    coherence point (MALL), tracked by vmcnt; s_waitcnt(0)+barrier
//    drains them (R6's cnt flush + ticket finalize, passing).
//
// R8 changes vs R7:
//  - GRID=256 x BLK=1024 (same 262,144 threads, NITER=32): cooperative
//    limit now needs only 1 blk/CU -> 2x margin vs runtime occupancy calc.
//  - pos scatter + cnt zeroing via atomicExch (RMW at coherence point),
//    not relaxed agent stores — closes the one unproven visibility link.
//  - hipLaunchCooperativeKernel return code CHECKED; on error fall back
//    to the proven R6 two-kernel pair.
//
// ws layout: [0,32K) pos floats; [32K, 32K+16392) u64 cnt[2048]+ticket;
// [56K) u32 grid-barrier cell (hipMemsetAsync'd to 0, poison-proof).

constexpr int N_POS = 8192;
constexpr int N_NEG = 4000;
constexpr int NSLOT = N_POS / 4;      // 2048 packed u64 count slots
constexpr int GRID  = 256;
constexpr int BLK   = 1024;
constexpr int NTHR  = GRID * BLK;     // 262,144 threads
constexpr int NITER = 32;             // 32*262,144*4 = 33.5M slots >= N_TOT
constexpr int CNT_BLOCKS = 512;       // fallback path

typedef int   vint4   __attribute__((ext_vector_type(4)));
typedef float vfloat4 __attribute__((ext_vector_type(4)));
typedef unsigned int u32;
typedef unsigned long long u64;

// ---------------------------------------------------------------- fused ----
__global__ __launch_bounds__(BLK, 4) void fused_mrr_kernel(
    const vint4* __restrict__ idx4, const float* __restrict__ pvs,
    float* __restrict__ pos, u64* __restrict__ cnt, u32* __restrict__ bar,
    float* __restrict__ out, int nvec) {
  __shared__ float pos_lds[N_POS];    // 32 KB
  __shared__ u32   lcnt[N_POS];       // 32 KB
  __shared__ float wsum[BLK / 64];
  __shared__ int   is_last;
  const int tid = threadIdx.x;
  const int gid = blockIdx.x * BLK + tid;
  const vfloat4* __restrict__ pv4 = (const vfloat4*)pvs;

#pragma unroll
  for (int i = 0; i < N_POS / BLK; ++i) lcnt[tid + i * BLK] = 0u;
  // zero cnt slots + ticket via RMW (lands at coherence point, vmcnt-tracked;
  // ordered before all post-barrier atomicAdds by the grid barrier)
  if (gid <= NSLOT) (void)atomicExch(&cnt[gid], 0ull);

  // ---- Phase A: stream idx ONCE; scatter pos (RMW); codes -> registers ----
  u32 code[2 * NITER];   // 4 x u16 row-codes per vint4 iter, fully unrolled
#define PA_ELEM(VX, PIDX, CO)                                            \
  {                                                                      \
    u32 c_ = ((VX) >= N_POS) ? ((u32)((VX)-N_POS) / (u32)N_NEG)          \
                             : 0xFFFFu;                                  \
    if ((VX) < N_POS) (void)atomicExch(&pos[VX], pvs[PIDX]);             \
    (CO) = c_;                                                           \
  }
#pragma unroll
  for (int i = 0; i < NITER; ++i) {
    const int j = gid + i * NTHR;
    if (j < nvec) {
      vint4 v = __builtin_nontemporal_load(&idx4[j]);
      u32 c0, c1, c2, c3;
      PA_ELEM(v.x, 4 * j + 0, c0)
      PA_ELEM(v.y, 4 * j + 1, c1)
      PA_ELEM(v.z, 4 * j + 2, c2)
      PA_ELEM(v.w, 4 * j + 3, c3)
      code[2 * i]     = c0 | (c1 << 16);
      code[2 * i + 1] = c2 | (c3 << 16);
    } else {
      code[2 * i]     = 0xFFFFFFFFu;
      code[2 * i + 1] = 0xFFFFFFFFu;
    }
  }
  for (int j = gid + NITER * NTHR; j < nvec; j += NTHR) {  // empty tail
    vint4 v = idx4[j];
    u32 dummy;
    PA_ELEM(v.x, 4 * j + 0, dummy)
    PA_ELEM(v.y, 4 * j + 1, dummy)
    PA_ELEM(v.z, 4 * j + 2, dummy)
    PA_ELEM(v.w, 4 * j + 3, dummy)
    (void)dummy;
  }
#undef PA_ELEM

  // ---- fence-free grid barrier (ticket pattern, proven mechanism) ----
  __builtin_amdgcn_s_waitcnt(0);   // all RMWs globally complete
  __syncthreads();
  if (tid == 0) {
    __hip_atomic_fetch_add(bar, 1u, __ATOMIC_RELAXED,
                           __HIP_MEMORY_SCOPE_AGENT);
    while (__hip_atomic_load(bar, __ATOMIC_RELAXED,
                             __HIP_MEMORY_SCOPE_AGENT) < (u32)GRID)
      __builtin_amdgcn_s_sleep(4);
  }
  __syncthreads();

  // ---- Phase B: stage pos (cache-bypassing loads), stream pv, count ----
#pragma unroll
  for (int i = 0; i < N_POS / BLK; ++i) {
    const int s = tid + i * BLK;
    pos_lds[s] = __hip_atomic_load(&pos[s], __ATOMIC_RELAXED,
                                   __HIP_MEMORY_SCOPE_AGENT);
  }
  __syncthreads();

#define PB_ELEM(R, XV)                                                   \
  if ((R) < (u32)N_POS && (XV) > pos_lds[R]) atomicAdd(&lcnt[R], 1u);
#pragma unroll
  for (int i = 0; i < NITER; ++i) {
    const int j = gid + i * NTHR;
    if (j < nvec) {
      vfloat4 x = __builtin_nontemporal_load(&pv4[j]);
      u32 w0 = code[2 * i], w1 = code[2 * i + 1];
      u32 r0 = w0 & 0xFFFFu, r1 = w0 >> 16;
      u32 r2 = w1 & 0xFFFFu, r3 = w1 >> 16;
      PB_ELEM(r0, x.x)
      PB_ELEM(r1, x.y)
      PB_ELEM(r2, x.z)
      PB_ELEM(r3, x.w)
    }
  }
  for (int j = gid + NITER * NTHR; j < nvec; j += NTHR) {  // empty tail
    vint4 v = idx4[j];
    vfloat4 x = pv4[j];
    u32 r0 = (v.x >= N_POS) ? ((u32)(v.x - N_POS) / (u32)N_NEG) : 0xFFFFu;
    u32 r1 = (v.y >= N_POS) ? ((u32)(v.y - N_POS) / (u32)N_NEG) : 0xFFFFu;
    u32 r2 = (v.z >= N_POS) ? ((u32)(v.z - N_POS) / (u32)N_NEG) : 0xFFFFu;
    u32 r3 = (v.w >= N_POS) ? ((u32)(v.w - N_POS) / (u32)N_NEG) : 0xFFFFu;
    PB_ELEM(r0, x.x)
    PB_ELEM(r1, x.y)
    PB_ELEM(r2, x.z)
    PB_ELEM(r3, x.w)
  }
#undef PB_ELEM
  __syncthreads();

  // Flush LDS counters -> packed u64 device-scope atomics (16-bit fields,
  // per-row totals <= 4000, never carry).
  for (int s = tid; s < NSLOT; s += BLK) {
    u32 c0 = lcnt[4 * s + 0], c1 = lcnt[4 * s + 1];
    u32 c2 = lcnt[4 * s + 2], c3 = lcnt[4 * s + 3];
    u64 p = (u64)c0 | ((u64)c1 << 16) | ((u64)c2 << 32) | ((u64)c3 << 48);
    if (p) atomicAdd(&cnt[s], p);
  }

  // ---- last-block-done finalize (fence-free ticket, proven in R6) ----
  __builtin_amdgcn_s_waitcnt(0);
  __syncthreads();
  if (tid == 0) {
    u64 prev = __hip_atomic_fetch_add(&cnt[NSLOT], 1ull, __ATOMIC_RELAXED,
                                      __HIP_MEMORY_SCOPE_AGENT);
    is_last = (prev == (u64)(GRID - 1));
  }
  __syncthreads();
  if (!is_last) return;

  float lsum = 0.f;
  for (int s = tid; s < NSLOT; s += BLK) {
    u64 p = __hip_atomic_load(&cnt[s], __ATOMIC_RELAXED,
                              __HIP_MEMORY_SCOPE_AGENT);
    float m0 = 1.0f / (float)(1u + (u32)(p & 0xFFFFu));
    float m1 = 1.0f / (float)(1u + (u32)((p >> 16) & 0xFFFFu));
    float m2 = 1.0f / (float)(1u + (u32)((p >> 32) & 0xFFFFu));
    float m3 = 1.0f / (float)(1u + (u32)((p >> 48) & 0xFFFFu));
    vfloat4 m = {m0, m1, m2, m3};
    *(vfloat4*)&out[1 + 4 * s] = m;
    lsum += m0 + m1 + m2 + m3;
  }
#pragma unroll
  for (int off = 32; off > 0; off >>= 1) lsum += __shfl_down(lsum, off, 64);
  if ((tid & 63) == 0) wsum[tid >> 6] = lsum;
  __syncthreads();
  if (tid == 0) {
    float tot = 0.f;
#pragma unroll
    for (int w = 0; w < BLK / 64; ++w) tot += wsum[w];
    out[0] = tot / (float)N_POS;
  }
}

// ------------------------------------------------- proven R6 fallback ----
__global__ __launch_bounds__(256) void scatter_pos_kernel(
    const vint4* __restrict__ idx4, const float* __restrict__ pv,
    float* __restrict__ pos, u64* __restrict__ cnt, int nvec) {
  const int gtid = blockIdx.x * 256 + threadIdx.x;
  if (gtid <= NSLOT) cnt[gtid] = 0ull;
  const int stride = gridDim.x * 256;
  int j = gtid;
#define SC_ELEM(V, JJ)                                   \
  if ((V).x < N_POS) pos[(V).x] = pv[4 * (JJ) + 0];      \
  if ((V).y < N_POS) pos[(V).y] = pv[4 * (JJ) + 1];      \
  if ((V).z < N_POS) pos[(V).z] = pv[4 * (JJ) + 2];      \
  if ((V).w < N_POS) pos[(V).w] = pv[4 * (JJ) + 3];
  for (; j + stride < nvec; j += 2 * stride) {
    vint4 a = idx4[j];
    vint4 b = idx4[j + stride];
    SC_ELEM(a, j)
    SC_ELEM(b, j + stride)
  }
  for (; j < nvec; j += stride) {
    vint4 a = idx4[j];
    SC_ELEM(a, j)
  }
#undef SC_ELEM
}

__global__ __launch_bounds__(1024) void count_kernel(
    const vint4* __restrict__ idx4, const vfloat4* __restrict__ pv4,
    const float* __restrict__ pos, u64* __restrict__ cnt,
    float* __restrict__ out, int nvec) {
  __shared__ float pos_lds[N_POS];
  __shared__ u32   lcnt[N_POS];
  __shared__ float wsum[16];
  __shared__ int is_last;
  for (int i = threadIdx.x; i < N_POS; i += 1024) {
    pos_lds[i] = pos[i];
    lcnt[i] = 0u;
  }
  __syncthreads();

  const int stride = gridDim.x * 1024;
  int j = blockIdx.x * 1024 + threadIdx.x;
#define CT_ELEM(IV, XV)                                              \
  if ((IV) >= N_POS) {                                               \
    unsigned r = (unsigned)((IV) - N_POS) / (unsigned)N_NEG;         \
    if ((XV) > pos_lds[r]) atomicAdd(&lcnt[r], 1u);                  \
  }
#define CT_VEC(V, X)                                                 \
  CT_ELEM((V).x, (X).x) CT_ELEM((V).y, (X).y)                        \
  CT_ELEM((V).z, (X).z) CT_ELEM((V).w, (X).w)
  for (; j + stride < nvec; j += 2 * stride) {
    vint4 va = idx4[j];
    vint4 vb = idx4[j + stride];
    vfloat4 xa = __builtin_nontemporal_load(&pv4[j]);
    vfloat4 xb = __builtin_nontemporal_load(&pv4[j + stride]);
    CT_VEC(va, xa)
    CT_VEC(vb, xb)
  }
  for (; j < nvec; j += stride) {
    vint4 va = idx4[j];
    vfloat4 xa = __builtin_nontemporal_load(&pv4[j]);
    CT_VEC(va, xa)
  }
#undef CT_VEC
#undef CT_ELEM
  __syncthreads();

  for (int s = threadIdx.x; s < NSLOT; s += 1024) {
    u32 c0 = lcnt[4 * s + 0], c1 = lcnt[4 * s + 1];
    u32 c2 = lcnt[4 * s + 2], c3 = lcnt[4 * s + 3];
    u64 p = (u64)c0 | ((u64)c1 << 16) | ((u64)c2 << 32) | ((u64)c3 << 48);
    if (p) atomicAdd(&cnt[s], p);
  }

  __builtin_amdgcn_s_waitcnt(0);
  __syncthreads();
  if (threadIdx.x == 0) {
    u64 prev = __hip_atomic_fetch_add(&cnt[NSLOT], 1ull, __ATOMIC_RELAXED,
                                      __HIP_MEMORY_SCOPE_AGENT);
    is_last = (prev == (u64)(gridDim.x - 1));
  }
  __syncthreads();
  if (!is_last) return;

  float lsum = 0.f;
  for (int s = threadIdx.x; s < NSLOT; s += 1024) {
    u64 p = __hip_atomic_load(&cnt[s], __ATOMIC_RELAXED,
                              __HIP_MEMORY_SCOPE_AGENT);
    float m0 = 1.0f / (float)(1u + (u32)(p & 0xFFFFu));
    float m1 = 1.0f / (float)(1u + (u32)((p >> 16) & 0xFFFFu));
    float m2 = 1.0f / (float)(1u + (u32)((p >> 32) & 0xFFFFu));
    float m3 = 1.0f / (float)(1u + (u32)((p >> 48) & 0xFFFFu));
    vfloat4 m = {m0, m1, m2, m3};
    *(vfloat4*)&out[1 + 4 * s] = m;
    lsum += m0 + m1 + m2 + m3;
  }
#pragma unroll
  for (int off = 32; off > 0; off >>= 1) lsum += __shfl_down(lsum, off, 64);
  if ((threadIdx.x & 63) == 0) wsum[threadIdx.x >> 6] = lsum;
  __syncthreads();
  if (threadIdx.x == 0) {
    float tot = 0.f;
#pragma unroll
    for (int w = 0; w < 16; ++w) tot += wsum[w];
    out[0] = tot / (float)N_POS;
  }
}

extern "C" void kernel_launch(void* const* d_in, const int* in_sizes, int n_in,
                              void* d_out, int out_size, void* d_ws,
                              size_t ws_size, hipStream_t stream) {
  const float* pv = (const float*)d_in[0];
  const vint4* idx4 = (const vint4*)d_in[1];
  float* out = (float*)d_out;
  float* pos = (float*)d_ws;
  u64* cnt = (u64*)((char*)d_ws + 32 * 1024);   // 2048 slots + ticket
  u32* bar = (u32*)((char*)d_ws + 56 * 1024);   // grid-barrier cell
  int nvec = in_sizes[0] / 4;                   // 8,194,048

  // Poison fill trashed ws: zero the barrier cell (stream-ordered, tiny).
  hipMemsetAsync(bar, 0, sizeof(u32), stream);

  void* args[] = {(void*)&idx4, (void*)&pv, (void*)&pos, (void*)&cnt,
                  (void*)&bar,  (void*)&out, (void*)&nvec};
  hipError_t e = hipLaunchCooperativeKernel((const void*)fused_mrr_kernel,
                                            dim3(GRID), dim3(BLK), args, 0,
                                            stream);
  if (e != hipSuccess) {
    // Proven two-kernel path (R6, 286 us).
    scatter_pos_kernel<<<2048, 256, 0, stream>>>(idx4, pv, pos, cnt, nvec);
    count_kernel<<<CNT_BLOCKS, 1024, 0, stream>>>(idx4, (const vfloat4*)pv,
                                                  pos, cnt, out, nvec);
  }
}